// Round 9
// baseline (152.512 us; speedup 1.0000x reference)
//
#include <hip/hip_runtime.h>
#include <hip/hip_bf16.h>

#define NB    2048
#define GPB   2                  // graphs per block
#define GRID  (NB / GPB)         // 1024 blocks -> all resident in one generation
#define NUMK  128
#define NE    1024
#define HID   32
#define ROWLEN (NUMK + NE + 2)
#define CAP   24                 // padded slots per row (unique srcs + self)
#define NPS   (NUMK * CAP)       // 3072
#define ASTRIDE 136              // bf16 elems per Â/x1T row (128 + 8 pad)
#define A1STRIDE 40              // bf16 elems per a1/W2T row (32 + 8 pad)
#define WSELF 1024               // widx of self-loop weight (1.0)
#define WPAD  1025               // widx of pad weight (0.0)
#define WVBASE 1026              // first vslot (chained dup merges)
#define MAXV  16
#define WTOT  (WVBASE + MAXV)

// slot encoding: src(7) | widx(11)<<7 | widx2(11)<<18 | prim(1)<<29
// pslot global layout (column-major): pslot_g[e*1024 + r*8 + l8] = psl[r][l8*3+e]
// vmeta: [0]=vcnt; [1+v] = a(11) | b(11)<<11  (wshp[WVBASE+v]=wshp[a]+wshp[b])
// NOTE: the edge template (pslot/vmeta) is graph-invariant; only weights differ.

using s8  = __attribute__((ext_vector_type(8))) short;   // 8 bf16 = 16 B
using f4  = __attribute__((ext_vector_type(4))) float;
using fl4 = __attribute__((ext_vector_type(4))) float;

static __device__ __forceinline__ unsigned short f2bf(float f) {
    unsigned u = __float_as_uint(f);
    unsigned r = (u + 0x7fffu + ((u >> 16) & 1u)) >> 16;   // RNE
    return (unsigned short)r;
}

// ---------------------------------------------------------------------------
// Setup (once): CSR by dst, per-row dedup into (widx, widx2 [, vslot chain]).
// ---------------------------------------------------------------------------
__global__ __launch_bounds__(1024) void build_csr_kernel(
    const int* __restrict__ ei,
    unsigned* __restrict__ pslot_g,    // [NPS] column-major (see above)
    unsigned* __restrict__ vmeta_g)    // [1 + MAXV]
{
    __shared__ unsigned cnt[NUMK], roff[NUMK + 1], cur[NUMK], incl[NUMK];
    __shared__ unsigned pk[NE];
    __shared__ unsigned psl[NUMK][CAP];
    __shared__ unsigned vc;
    const int t = threadIdx.x;

    if (t < NUMK) cnt[t] = 0u;
    if (t == 0) vc = 0u;
    __syncthreads();
    const int dst = ei[NE + t] & (NUMK - 1);
    atomicAdd(&cnt[dst], 1u);
    __syncthreads();

    if (t < NUMK) {                              // exclusive scan (2 wave scans)
        unsigned v = cnt[t];
        #pragma unroll
        for (int d = 1; d < 64; d <<= 1) {
            unsigned u = __shfl_up(v, d, 64);
            if ((t & 63) >= d) v += u;
        }
        incl[t] = v;
    }
    __syncthreads();
    if (t < NUMK) {
        const unsigned base = (t >= 64) ? incl[63] : 0u;
        const unsigned off  = base + incl[t] - cnt[t];
        roff[t] = off; cur[t] = off;
    }
    if (t == 0) roff[NUMK] = (unsigned)NE;
    __syncthreads();

    {
        const int src = ei[t] & (NUMK - 1);
        const unsigned pos = atomicAdd(&cur[dst], 1u);
        pk[pos] = (unsigned)src | ((unsigned)t << 16);
    }
    __syncthreads();

    if (t < NUMK) {
        int np = 0;
        auto addOrMerge = [&](unsigned s, unsigned eid) {
            int j = -1;
            for (int i = 0; i < np; ++i)
                if ((psl[t][i] & 127u) == s) { j = i; break; }
            if (j >= 0) {
                const unsigned slot = psl[t][j];
                const unsigned w2 = (slot >> 18) & 0x7FFu;
                if (w2 == (unsigned)WPAD) {
                    psl[t][j] = (slot & ~(0x7FFu << 18)) | (eid << 18);
                } else {
                    const unsigned v = atomicAdd(&vc, 1u);
                    if (v < (unsigned)MAXV) {
                        vmeta_g[1 + v] = w2 | (eid << 11);
                        psl[t][j] = (slot & ~(0x7FFu << 18))
                                  | (((unsigned)WVBASE + v) << 18);
                    }
                }
            } else if (np < CAP) {
                psl[t][np++] = s | (eid << 7)
                             | ((unsigned)WPAD << 18) | (1u << 29);
            }
        };
        const unsigned k0 = roff[t], k1 = roff[t + 1];
        for (unsigned k = k0; k < k1; ++k)
            addOrMerge(pk[k] & 127u, pk[k] >> 16);
        addOrMerge((unsigned)t, (unsigned)WSELF);        // self-loop, w = 1
        for (int i = np; i < CAP; ++i)                   // pads: w = 0, prim = 0
            psl[t][i] = ((unsigned)WPAD << 7) | ((unsigned)WPAD << 18);
    }
    __syncthreads();

    for (int i = t; i < NPS; i += 1024) {
        const int e = i >> 10, rem = i & 1023;
        const int r = rem >> 3, l8 = rem & 7;
        pslot_g[i] = psl[r][l8 * 3 + e];
    }
    if (t == 0) vmeta_g[0] = (vc <= (unsigned)MAXV) ? vc : (unsigned)MAXV;
}

// ---------------------------------------------------------------------------
// Main: one block (512 thr = 8 waves) per TWO graphs; ~36.4 KB LDS, 4
// blocks/CU -> all 1024 blocks resident in ONE generation (probes the
// dispatch-rate hypothesis). Graph-invariant state (su regs, W2T, w1s..,
// panel zero) staged once; per-graph restage is 4.5 KB (wshp+pbuf) from
// registers prefetched during the previous graph's MFMA section.
// ---------------------------------------------------------------------------
__global__ __launch_bounds__(512, 8) void gcn_main_kernel(
    const float* __restrict__ Hx,
    const float* __restrict__ W1, const float* __restrict__ b1,
    const float* __restrict__ W2, const float* __restrict__ b2,
    const float* __restrict__ W3, const float* __restrict__ b3,
    const unsigned* __restrict__ pslot_g,
    const unsigned* __restrict__ vmeta_g,
    float* __restrict__ out)
{
    __shared__ __align__(16) short Ab[64 * ASTRIDE];    // 17408 B (Â panel)
    __shared__ __align__(16) short uni[5120];           // 10240 B (x1T / a1bf)
    __shared__ __align__(16) float wshp[WTOT];          //  4168 B
    __shared__ __align__(16) short W2T[HID * A1STRIDE]; //  2560 B
    __shared__ float pbuf[NUMK], degv[NUMK], a0s[NUMK]; //  1536 B
    __shared__ float w1s[HID], b1s[HID], b2s[HID], w3s[HID];   // 512 B

    const int tid = threadIdx.x;                 // 0..511
    const int grp = tid >> 3, l8 = tid & 7;      // 64 row groups x 8 lanes
    const int wv = tid >> 6, l = tid & 15, q = (tid & 63) >> 4;
    const int mt = wv >> 1, nt = wv & 1;         // MFMA tile assignment

    // ---- once-per-block staging ----
    unsigned su[6];                  // graph-invariant slots (template shared)
    #pragma unroll
    for (int p = 0; p < 2; ++p)
        #pragma unroll
        for (int e = 0; e < 3; ++e)
            su[p * 3 + e] = pslot_g[(e << 10) + (p << 9) + tid];   // coalesced
    const float b3v = b3[0];
    const unsigned vcnt = vmeta_g[0];

    // graph-0 per-graph data into regs
    const float* rowp0 = Hx + (size_t)blockIdx.x * ROWLEN;
    float2 wcur = *(const float2*)&rowp0[NUMK + tid * 2];
    float  pcur = (tid < NUMK) ? rowp0[tid] : 0.f;
    float2 wnxt = {0.f, 0.f};
    float  pnxt = 0.f;

    for (int t2 = tid; t2 < (64 * ASTRIDE) / 8; t2 += 512)
        *(s8*)&Ab[t2 * 8] = (s8)0;                       // zero panel A (g0)
    for (int t2 = tid; t2 < HID * HID; t2 += 512) {
        const int k = t2 >> 5, n = t2 & 31;
        W2T[n * A1STRIDE + k] = (short)f2bf(W2[t2]);
    }
    if (tid < HID) {
        w1s[tid] = W1[tid]; b1s[tid] = b1[tid];
        b2s[tid] = b2[tid]; w3s[tid] = W3[tid];
    }

    #pragma unroll 1
    for (int gi = 0; gi < GPB; ++gi) {
        const int graph = blockIdx.x + gi * GRID;

        // ---- per-graph LDS staging from regs ----
        *(float2*)&wshp[tid * 2] = wcur;
        if (tid == 0) { wshp[WSELF] = 1.0f; wshp[WPAD] = 0.0f; }
        if (tid < NUMK) pbuf[tid] = pcur;
        __syncthreads();                               // B1

        // ---- vslot prepass (chained >=3 dups; usually empty; vcnt uniform) ----
        if (vcnt) {
            if (tid == 0) {
                for (unsigned v = 0; v < vcnt; ++v) {
                    const unsigned e = vmeta_g[1 + v];
                    wshp[WVBASE + v] = wshp[e & 0x7FFu] + wshp[(e >> 11) & 0x7FFu];
                }
            }
            __syncthreads();
        }

        // ---- P2: merged slot weights (into nvr) + deg -> dinv ----
        float nvr[6];
        #pragma unroll
        for (int p = 0; p < 2; ++p) {
            float d = 0.f;
            #pragma unroll
            for (int e = 0; e < 3; ++e) {
                const int i = p * 3 + e;
                const unsigned u = su[i];
                nvr[i] = wshp[(u >> 7) & 0x7FFu] + wshp[(u >> 18) & 0x7FFu];
                d += nvr[i];
            }
            d += __shfl_xor(d, 1, 8);
            d += __shfl_xor(d, 2, 8);
            d += __shfl_xor(d, 4, 8);
            if (l8 == 0) degv[grp + (p << 6)] = rsqrtf(d);   // deg >= 1
        }
        __syncthreads();                               // B2

        // ---- P4: norms (in nvr) + panel-A scatter + a0 = Â·p ----
        #pragma unroll
        for (int p = 0; p < 2; ++p) {
            const int r = grp + (p << 6);
            const float dr = degv[r];
            float acc = 0.f;
            #pragma unroll
            for (int e = 0; e < 3; ++e) {
                const int i = p * 3 + e;
                const unsigned u = su[i];
                const int s = (int)(u & 127u);
                const float nv = (u >> 29) ? dr * degv[s] * nvr[i] : 0.f;
                if ((u >> 29) && p == 0)                 // panel A rows 0..63
                    Ab[r * ASTRIDE + s] = (short)f2bf(nv);
                nvr[i] = nv;
                acc = fmaf(nv, pbuf[s], acc);
            }
            acc += __shfl_xor(acc, 1, 8);
            acc += __shfl_xor(acc, 2, 8);
            acc += __shfl_xor(acc, 4, 8);
            if (l8 == 0) a0s[r] = acc;
        }
        __syncthreads();                               // B3

        // ---- prefetch next graph's per-graph data (hidden under MFMA) ----
        if (gi + 1 < GPB) {
            const float* rown = Hx + (size_t)(graph + GRID) * ROWLEN;
            wnxt = *(const float2*)&rown[NUMK + tid * 2];
            pnxt = (tid < NUMK) ? rown[tid] : 0.f;
        }

        // ---- x1T build: x1T[j][k] = relu(a0[k]*w1[j]+b1[j]), bf16 ----
        short* x1T = uni;
        {
            const int jj = tid >> 4, k0 = (tid & 15) << 3;
            const float w1j = w1s[jj], b1j = b1s[jj];
            const fl4 av0 = *(const fl4*)&a0s[k0];
            const fl4 av1 = *(const fl4*)&a0s[k0 + 4];
            union { unsigned u[4]; s8 v; } P;
            #pragma unroll
            for (int h = 0; h < 4; ++h) {
                const float e0 = (h < 2) ? av0[2 * h]     : av1[2 * h - 4];
                const float e1 = (h < 2) ? av0[2 * h + 1] : av1[2 * h - 3];
                const float x0 = fmaxf(fmaf(e0, w1j, b1j), 0.f);
                const float x1 = fmaxf(fmaf(e1, w1j, b1j), 0.f);
                P.u[h] = (unsigned)f2bf(x0) | ((unsigned)f2bf(x1) << 16);
            }
            *(s8*)&x1T[jj * ASTRIDE + k0] = P.v;
        }
        __syncthreads();                               // B4

        // ---- MFMA panel A: wave = (m-tile mt, n-tile nt) ----
        f4 accA = {0.f, 0.f, 0.f, 0.f}, accB = {0.f, 0.f, 0.f, 0.f};
        const int arow = (mt << 4) + l;
        const int brow = (nt << 4) + l;
        #pragma unroll
        for (int ks = 0; ks < 4; ++ks) {
            const int kb = (ks << 5) + (q << 3);
            const s8 A = *(const s8*)&Ab[arow * ASTRIDE + kb];
            const s8 B = *(const s8*)&x1T[brow * ASTRIDE + kb];
            accA = __builtin_amdgcn_mfma_f32_16x16x32_bf16(A, B, accA, 0, 0, 0);
        }
        __syncthreads();                               // B5

        // ---- panel B: zero + scatter (row grp by its own 8 lanes) ----
        {
            const int c0 = l8 << 4;
            const s8 z = (s8)0;
            *(s8*)&Ab[grp * ASTRIDE + c0]     = z;
            *(s8*)&Ab[grp * ASTRIDE + c0 + 8] = z;
            #pragma unroll
            for (int e = 0; e < 3; ++e) {
                const unsigned u = su[3 + e];
                if (u >> 29)
                    Ab[grp * ASTRIDE + (int)(u & 127u)] = (short)f2bf(nvr[3 + e]);
            }
        }
        __syncthreads();                               // B6

        // ---- MFMA panel B ----
        #pragma unroll
        for (int ks = 0; ks < 4; ++ks) {
            const int kb = (ks << 5) + (q << 3);
            const s8 A = *(const s8*)&Ab[arow * ASTRIDE + kb];
            const s8 B = *(const s8*)&x1T[brow * ASTRIDE + kb];
            accB = __builtin_amdgcn_mfma_f32_16x16x32_bf16(A, B, accB, 0, 0, 0);
        }
        __syncthreads();                               // B7 (Ab + x1T reads done)

        // ---- zero panel A for next graph (Ab dead until next P4) ----
        if (gi + 1 < GPB) {
            for (int t2 = tid; t2 < (64 * ASTRIDE) / 8; t2 += 512)
                *(s8*)&Ab[t2 * 8] = (s8)0;
        }

        // ---- P5': a1 -> LDS bf16 (union region) ----
        short* a1bf = uni;
        #pragma unroll
        for (int r = 0; r < 4; ++r) {
            const int row = (mt << 4) + (q << 2) + r;
            const int col = (nt << 4) + l;
            a1bf[row * A1STRIDE + col]        = (short)f2bf(accA[r]);
            a1bf[(64 + row) * A1STRIDE + col] = (short)f2bf(accB[r]);
        }
        __syncthreads();                               // B8

        // ---- P7: x2 = relu(a1@W2+b2); s = x2@W3 (16-wide shfl reduce) ----
        float* sbuf = degv;                            // dinv dead after P4
        {
            f4 ac20 = {0.f,0.f,0.f,0.f}, ac21 = {0.f,0.f,0.f,0.f};
            const s8 A0  = *(const s8*)&a1bf[((wv << 4) + l) * A1STRIDE + (q << 3)];
            const s8 Bw0 = *(const s8*)&W2T[l * A1STRIDE + (q << 3)];
            const s8 Bw1 = *(const s8*)&W2T[(16 + l) * A1STRIDE + (q << 3)];
            ac20 = __builtin_amdgcn_mfma_f32_16x16x32_bf16(A0, Bw0, ac20, 0, 0, 0);
            ac21 = __builtin_amdgcn_mfma_f32_16x16x32_bf16(A0, Bw1, ac21, 0, 0, 0);

            const float b2a = b2s[l], b2b = b2s[l + 16];
            const float w3a = w3s[l], w3b = w3s[l + 16];
            #pragma unroll
            for (int r = 0; r < 4; ++r) {
                const float v0 = fmaxf(ac20[r] + b2a, 0.f);
                const float v1 = fmaxf(ac21[r] + b2b, 0.f);
                float sv = v0 * w3a + v1 * w3b;
                #pragma unroll
                for (int m = 1; m < 16; m <<= 1) sv += __shfl_xor(sv, m, 16);
                if (l == 0) sbuf[(wv << 4) + (q << 2) + r] = sv;
            }
        }
        __syncthreads();                               // B9

        // ---- P8: out = Â·s (norms from regs) ----
        #pragma unroll
        for (int p = 0; p < 2; ++p) {
            const int r = grp + (p << 6);
            float acc8 = 0.f;
            #pragma unroll
            for (int e = 0; e < 3; ++e)
                acc8 = fmaf(nvr[p * 3 + e], sbuf[su[p * 3 + e] & 127u], acc8);
            acc8 += __shfl_xor(acc8, 1, 8);
            acc8 += __shfl_xor(acc8, 2, 8);
            acc8 += __shfl_xor(acc8, 4, 8);
            if (l8 == 0) out[(size_t)graph * NUMK + r] = acc8 + b3v;
        }

        // ---- rotate prefetched regs; protect degv/wshp/pbuf for next graph ----
        if (gi + 1 < GPB) {
            wcur = wnxt; pcur = pnxt;
            __syncthreads();                           // B10 (sbuf reads done)
        }
    }
}

extern "C" void kernel_launch(void* const* d_in, const int* in_sizes, int n_in,
                              void* d_out, int out_size, void* d_ws, size_t ws_size,
                              hipStream_t stream) {
    const float* Hx = (const float*)d_in[0];
    const int*   ei = (const int*)d_in[1];
    const float* W1 = (const float*)d_in[2];
    const float* b1 = (const float*)d_in[3];
    const float* W2 = (const float*)d_in[4];
    const float* b2 = (const float*)d_in[5];
    const float* W3 = (const float*)d_in[6];
    const float* b3 = (const float*)d_in[7];
    float* out = (float*)d_out;

    unsigned* pslot = (unsigned*)d_ws;                 // [NPS]
    unsigned* vmeta = pslot + NPS;                     // [1 + MAXV]

    build_csr_kernel<<<1, 1024, 0, stream>>>(ei, pslot, vmeta);
    gcn_main_kernel<<<GRID, 512, 0, stream>>>(Hx, W1, b1, W2, b2, W3, b3,
                                              pslot, vmeta, out);
}

// Round 10
// 111.878 us; speedup vs baseline: 1.3632x; 1.3632x over previous
//
#include <hip/hip_runtime.h>
#include <hip/hip_bf16.h>

#define NB    2048
#define GPB   2                  // graphs per block
#define GRID  (NB / GPB)         // 1024 blocks = 256 CUs x 4 resident
#define NUMK  128
#define NE    1024
#define HID   32
#define ROWLEN (NUMK + NE + 2)
#define CAP   24                 // padded slots per row (unique srcs + self)
#define NPS   (NUMK * CAP)       // 3072
#define ASTRIDE 136              // bf16 elems per Â/x1T row (128 + 8 pad)
#define A1STRIDE 40              // bf16 elems per a1/W2T row (32 + 8 pad)
#define WSELF 1024               // widx of self-loop weight (1.0)
#define WPAD  1025               // widx of pad weight (0.0)
#define WVBASE 1026              // first vslot (chained dup merges)
#define MAXV  16
#define WTOT  (WVBASE + MAXV)

// slot encoding: src(7) | widx(11)<<7 | widx2(11)<<18 | prim(1)<<29
// pslot global layout (column-major): pslot_g[e*1024 + r*8 + l8] = psl[r][l8*3+e]
// vmeta: [0]=vcnt; [1+v] = a(11) | b(11)<<11  (wshp[WVBASE+v]=wshp[a]+wshp[b])
// Template (pslot/vmeta) is graph-invariant; only weights/signals differ.

using s8  = __attribute__((ext_vector_type(8))) short;   // 8 bf16 = 16 B
using f4  = __attribute__((ext_vector_type(4))) float;
using fl4 = __attribute__((ext_vector_type(4))) float;

static __device__ __forceinline__ unsigned short f2bf(float f) {
    unsigned u = __float_as_uint(f);
    unsigned r = (u + 0x7fffu + ((u >> 16) & 1u)) >> 16;   // RNE
    return (unsigned short)r;
}

// ---------------------------------------------------------------------------
// Setup (once): CSR by dst, per-row dedup into (widx, widx2 [, vslot chain]).
// ---------------------------------------------------------------------------
__global__ __launch_bounds__(1024) void build_csr_kernel(
    const int* __restrict__ ei,
    unsigned* __restrict__ pslot_g,    // [NPS] column-major (see above)
    unsigned* __restrict__ vmeta_g)    // [1 + MAXV]
{
    __shared__ unsigned cnt[NUMK], roff[NUMK + 1], cur[NUMK], incl[NUMK];
    __shared__ unsigned pk[NE];
    __shared__ unsigned psl[NUMK][CAP];
    __shared__ unsigned vc;
    const int t = threadIdx.x;

    if (t < NUMK) cnt[t] = 0u;
    if (t == 0) vc = 0u;
    __syncthreads();
    const int dst = ei[NE + t] & (NUMK - 1);
    atomicAdd(&cnt[dst], 1u);
    __syncthreads();

    if (t < NUMK) {                              // exclusive scan (2 wave scans)
        unsigned v = cnt[t];
        #pragma unroll
        for (int d = 1; d < 64; d <<= 1) {
            unsigned u = __shfl_up(v, d, 64);
            if ((t & 63) >= d) v += u;
        }
        incl[t] = v;
    }
    __syncthreads();
    if (t < NUMK) {
        const unsigned base = (t >= 64) ? incl[63] : 0u;
        const unsigned off  = base + incl[t] - cnt[t];
        roff[t] = off; cur[t] = off;
    }
    if (t == 0) roff[NUMK] = (unsigned)NE;
    __syncthreads();

    {
        const int src = ei[t] & (NUMK - 1);
        const unsigned pos = atomicAdd(&cur[dst], 1u);
        pk[pos] = (unsigned)src | ((unsigned)t << 16);
    }
    __syncthreads();

    if (t < NUMK) {
        int np = 0;
        auto addOrMerge = [&](unsigned s, unsigned eid) {
            int j = -1;
            for (int i = 0; i < np; ++i)
                if ((psl[t][i] & 127u) == s) { j = i; break; }
            if (j >= 0) {
                const unsigned slot = psl[t][j];
                const unsigned w2 = (slot >> 18) & 0x7FFu;
                if (w2 == (unsigned)WPAD) {
                    psl[t][j] = (slot & ~(0x7FFu << 18)) | (eid << 18);
                } else {
                    const unsigned v = atomicAdd(&vc, 1u);
                    if (v < (unsigned)MAXV) {
                        vmeta_g[1 + v] = w2 | (eid << 11);
                        psl[t][j] = (slot & ~(0x7FFu << 18))
                                  | (((unsigned)WVBASE + v) << 18);
                    }
                }
            } else if (np < CAP) {
                psl[t][np++] = s | (eid << 7)
                             | ((unsigned)WPAD << 18) | (1u << 29);
            }
        };
        const unsigned k0 = roff[t], k1 = roff[t + 1];
        for (unsigned k = k0; k < k1; ++k)
            addOrMerge(pk[k] & 127u, pk[k] >> 16);
        addOrMerge((unsigned)t, (unsigned)WSELF);        // self-loop, w = 1
        for (int i = np; i < CAP; ++i)                   // pads: w = 0, prim = 0
            psl[t][i] = ((unsigned)WPAD << 7) | ((unsigned)WPAD << 18);
    }
    __syncthreads();

    for (int i = t; i < NPS; i += 1024) {
        const int e = i >> 10, rem = i & 1023;
        const int r = rem >> 3, l8 = rem & 7;
        pslot_g[i] = psl[r][l8 * 3 + e];
    }
    if (t == 0) vmeta_g[0] = (vc <= (unsigned)MAXV) ? vc : (unsigned)MAXV;
}

// ---------------------------------------------------------------------------
// Main: one block (256 thr = 4 waves) per TWO graphs; 1024 blocks = exactly
// one resident generation (4 blocks/CU x 256 CU). launch_bounds(256,4) ->
// 128-reg budget: NO scratch spills (R9's 113 MB spill traffic was the
// (512,8) 32-VGPR cap). Per-thread maps are the R7-validated 256-thread
// versions; per-graph restage = 4.5 KB LDS from prefetched registers.
// ---------------------------------------------------------------------------
__global__ __launch_bounds__(256, 4) void gcn_main_kernel(
    const float* __restrict__ Hx,
    const float* __restrict__ W1, const float* __restrict__ b1,
    const float* __restrict__ W2, const float* __restrict__ b2,
    const float* __restrict__ W3, const float* __restrict__ b3,
    const unsigned* __restrict__ pslot_g,
    const unsigned* __restrict__ vmeta_g,
    float* __restrict__ out)
{
    __shared__ __align__(16) short Ab[64 * ASTRIDE];    // 17408 B (Â panel)
    __shared__ __align__(16) short uni[5120];           // 10240 B (x1T / a1bf)
    __shared__ __align__(16) float wshp[WTOT];          //  4168 B
    __shared__ __align__(16) short W2T[HID * A1STRIDE]; //  2560 B
    __shared__ float pbuf[NUMK], degv[NUMK], a0s[NUMK]; //  1536 B
    __shared__ float w1s[HID], b1s[HID], b2s[HID], w3s[HID];   // 512 B
    // total ~36.4 KB -> 4 blocks/CU

    const int tid = threadIdx.x;                 // 0..255
    const int grp = tid >> 3, l8 = tid & 7;      // 32 row groups x 8 lanes
    const int wv = tid >> 6, l = tid & 15, q = (tid & 63) >> 4;

    // ---- once-per-block staging ----
    unsigned su[12];                 // rows {grp+32p} x 3 slots (graph-invariant)
    #pragma unroll
    for (int p = 0; p < 4; ++p)
        #pragma unroll
        for (int e = 0; e < 3; ++e)
            su[p * 3 + e] = pslot_g[(e << 10) + (p << 8) + tid];   // coalesced
    const float b3v = b3[0];
    const unsigned vcnt = vmeta_g[0];

    // graph-0 per-graph data into regs
    const float* rowp0 = Hx + (size_t)blockIdx.x * ROWLEN;
    fl4  wcur = *(const fl4*)&rowp0[NUMK + tid * 4];
    float pcur = (tid < NUMK) ? rowp0[tid] : 0.f;
    fl4  wnxt = {0.f, 0.f, 0.f, 0.f};
    float pnxt = 0.f;

    for (int t2 = tid; t2 < (64 * ASTRIDE) / 8; t2 += 256)
        *(s8*)&Ab[t2 * 8] = (s8)0;                       // zero panel A (g0)
    for (int t2 = tid; t2 < HID * HID; t2 += 256) {
        const int k = t2 >> 5, n = t2 & 31;
        W2T[n * A1STRIDE + k] = (short)f2bf(W2[t2]);
    }
    if (tid < HID) {
        w1s[tid] = W1[tid]; b1s[tid] = b1[tid];
        b2s[tid] = b2[tid]; w3s[tid] = W3[tid];
    }

    #pragma unroll 1
    for (int gi = 0; gi < GPB; ++gi) {
        const int graph = blockIdx.x + gi * GRID;

        // ---- per-graph LDS staging from regs ----
        *(fl4*)&wshp[tid * 4] = wcur;
        if (tid == 0) { wshp[WSELF] = 1.0f; wshp[WPAD] = 0.0f; }
        if (tid < NUMK) pbuf[tid] = pcur;
        __syncthreads();                               // B1

        // ---- vslot prepass (chained >=3 dups; vcnt uniform, usually small) ----
        if (vcnt) {
            if (tid == 0) {
                for (unsigned v = 0; v < vcnt; ++v) {
                    const unsigned e = vmeta_g[1 + v];
                    wshp[WVBASE + v] = wshp[e & 0x7FFu] + wshp[(e >> 11) & 0x7FFu];
                }
            }
            __syncthreads();
        }

        // ---- P2: merged slot weights (into nvr) + deg -> dinv ----
        float nvr[12];
        #pragma unroll
        for (int p = 0; p < 4; ++p) {
            float d = 0.f;
            #pragma unroll
            for (int e = 0; e < 3; ++e) {
                const int i = p * 3 + e;
                const unsigned u = su[i];
                nvr[i] = wshp[(u >> 7) & 0x7FFu] + wshp[(u >> 18) & 0x7FFu];
                d += nvr[i];
            }
            d += __shfl_xor(d, 1, 8);
            d += __shfl_xor(d, 2, 8);
            d += __shfl_xor(d, 4, 8);
            if (l8 == 0) degv[grp + (p << 5)] = rsqrtf(d);   // deg >= 1
        }
        __syncthreads();                               // B2

        // ---- P4: norms (in nvr) + panel-A scatter (rows 0..63) + a0 = Â·p ----
        #pragma unroll
        for (int p = 0; p < 4; ++p) {
            const int r = grp + (p << 5);
            const float dr = degv[r];
            float acc = 0.f;
            #pragma unroll
            for (int e = 0; e < 3; ++e) {
                const int i = p * 3 + e;
                const unsigned u = su[i];
                const int s = (int)(u & 127u);
                const float nv = (u >> 29) ? dr * degv[s] * nvr[i] : 0.f;
                if ((u >> 29) && p < 2)
                    Ab[r * ASTRIDE + s] = (short)f2bf(nv);
                nvr[i] = nv;
                acc = fmaf(nv, pbuf[s], acc);
            }
            acc += __shfl_xor(acc, 1, 8);
            acc += __shfl_xor(acc, 2, 8);
            acc += __shfl_xor(acc, 4, 8);
            if (l8 == 0) a0s[r] = acc;
        }
        __syncthreads();                               // B3

        // ---- prefetch next graph's data (hidden under MFMA section) ----
        if (gi + 1 < GPB) {
            const float* rown = Hx + (size_t)(graph + GRID) * ROWLEN;
            wnxt = *(const fl4*)&rown[NUMK + tid * 4];
            pnxt = (tid < NUMK) ? rown[tid] : 0.f;
        }

        // ---- x1T build: x1T[j][k] = relu(a0[k]*w1[j]+b1[j]), bf16 ----
        short* x1T = uni;
        {
            const int jj = tid >> 3, k0 = (tid & 7) << 4;
            const float w1j = w1s[jj], b1j = b1s[jj];
            float tmp[16];
            #pragma unroll
            for (int c = 0; c < 4; ++c) {
                const fl4 av = *(const fl4*)&a0s[k0 + 4 * c];
                #pragma unroll
                for (int e = 0; e < 4; ++e) tmp[c * 4 + e] = av[e];
            }
            union { unsigned u[8]; s8 v2[2]; } P;
            #pragma unroll
            for (int h = 0; h < 8; ++h) {
                const float x0 = fmaxf(fmaf(tmp[2 * h],     w1j, b1j), 0.f);
                const float x1 = fmaxf(fmaf(tmp[2 * h + 1], w1j, b1j), 0.f);
                P.u[h] = (unsigned)f2bf(x0) | ((unsigned)f2bf(x1) << 16);
            }
            *(s8*)&x1T[jj * ASTRIDE + k0]     = P.v2[0];
            *(s8*)&x1T[jj * ASTRIDE + k0 + 8] = P.v2[1];
        }
        __syncthreads();                               // B4

        // ---- MFMA panel A: rows 16wv+l; both n-tiles per wave ----
        f4 accm[2][2] = {{{0.f,0.f,0.f,0.f},{0.f,0.f,0.f,0.f}},
                         {{0.f,0.f,0.f,0.f},{0.f,0.f,0.f,0.f}}};
        const int ar = (wv << 4) + l;
        #pragma unroll
        for (int ks = 0; ks < 4; ++ks) {
            const int kb = (ks << 5) + (q << 3);
            const s8 A  = *(const s8*)&Ab[ar * ASTRIDE + kb];
            const s8 B0 = *(const s8*)&x1T[l * ASTRIDE + kb];
            const s8 B1 = *(const s8*)&x1T[(16 + l) * ASTRIDE + kb];
            accm[0][0] = __builtin_amdgcn_mfma_f32_16x16x32_bf16(A, B0, accm[0][0], 0, 0, 0);
            accm[0][1] = __builtin_amdgcn_mfma_f32_16x16x32_bf16(A, B1, accm[0][1], 0, 0, 0);
        }
        __syncthreads();                               // B5 (panel-A reads done)

        // ---- panel B: zero + scatter (rows grp & grp+32 by their 8 lanes) ----
        {
            const int c0 = l8 << 4;
            const s8 z = (s8)0;
            *(s8*)&Ab[grp * ASTRIDE + c0]            = z;
            *(s8*)&Ab[grp * ASTRIDE + c0 + 8]        = z;
            *(s8*)&Ab[(grp + 32) * ASTRIDE + c0]     = z;
            *(s8*)&Ab[(grp + 32) * ASTRIDE + c0 + 8] = z;
            #pragma unroll
            for (int p = 2; p < 4; ++p) {
                #pragma unroll
                for (int e = 0; e < 3; ++e) {
                    const int i = p * 3 + e;
                    const unsigned u = su[i];
                    if (u >> 29) {
                        const int pr = grp + ((p - 2) << 5);
                        Ab[pr * ASTRIDE + (int)(u & 127u)] = (short)f2bf(nvr[i]);
                    }
                }
            }
        }
        __syncthreads();                               // B6

        // ---- MFMA panel B ----
        #pragma unroll
        for (int ks = 0; ks < 4; ++ks) {
            const int kb = (ks << 5) + (q << 3);
            const s8 A  = *(const s8*)&Ab[ar * ASTRIDE + kb];
            const s8 B0 = *(const s8*)&x1T[l * ASTRIDE + kb];
            const s8 B1 = *(const s8*)&x1T[(16 + l) * ASTRIDE + kb];
            accm[1][0] = __builtin_amdgcn_mfma_f32_16x16x32_bf16(A, B0, accm[1][0], 0, 0, 0);
            accm[1][1] = __builtin_amdgcn_mfma_f32_16x16x32_bf16(A, B1, accm[1][1], 0, 0, 0);
        }
        __syncthreads();                               // B7 (Ab + x1T reads done)

        // ---- zero panel A for next graph (Ab dead until next P4) ----
        if (gi + 1 < GPB) {
            for (int t2 = tid; t2 < (64 * ASTRIDE) / 8; t2 += 256)
                *(s8*)&Ab[t2 * 8] = (s8)0;
        }

        // ---- P5': a1 -> LDS bf16 (union region; own-wave rows) ----
        short* a1bf = uni;
        #pragma unroll
        for (int P = 0; P < 2; ++P)
            #pragma unroll
            for (int nt = 0; nt < 2; ++nt)
                #pragma unroll
                for (int r = 0; r < 4; ++r) {
                    const int i = (P << 6) + (wv << 4) + (q << 2) + r;
                    const int j = (nt << 4) + l;
                    a1bf[i * A1STRIDE + j] = (short)f2bf(accm[P][nt][r]);
                }

        // ---- P7: x2 = relu(a1@W2+b2); s = x2@W3 (same-wave rows; shfl) ----
        float* sbuf = degv;                            // dinv dead after P4
        {
            f4 ac2[2][2] = {{{0.f,0.f,0.f,0.f},{0.f,0.f,0.f,0.f}},
                            {{0.f,0.f,0.f,0.f},{0.f,0.f,0.f,0.f}}};
            const s8 A0  = *(const s8*)&a1bf[((wv << 4) + l) * A1STRIDE + (q << 3)];
            const s8 A1  = *(const s8*)&a1bf[(64 + (wv << 4) + l) * A1STRIDE + (q << 3)];
            const s8 Bw0 = *(const s8*)&W2T[l * A1STRIDE + (q << 3)];
            const s8 Bw1 = *(const s8*)&W2T[(16 + l) * A1STRIDE + (q << 3)];
            ac2[0][0] = __builtin_amdgcn_mfma_f32_16x16x32_bf16(A0, Bw0, ac2[0][0], 0, 0, 0);
            ac2[0][1] = __builtin_amdgcn_mfma_f32_16x16x32_bf16(A0, Bw1, ac2[0][1], 0, 0, 0);
            ac2[1][0] = __builtin_amdgcn_mfma_f32_16x16x32_bf16(A1, Bw0, ac2[1][0], 0, 0, 0);
            ac2[1][1] = __builtin_amdgcn_mfma_f32_16x16x32_bf16(A1, Bw1, ac2[1][1], 0, 0, 0);

            const float b2a = b2s[l], b2b = b2s[l + 16];
            const float w3a = w3s[l], w3b = w3s[l + 16];
            #pragma unroll
            for (int mt = 0; mt < 2; ++mt)
                #pragma unroll
                for (int r = 0; r < 4; ++r) {
                    const float v0 = fmaxf(ac2[mt][0][r] + b2a, 0.f);
                    const float v1 = fmaxf(ac2[mt][1][r] + b2b, 0.f);
                    float sv = v0 * w3a + v1 * w3b;
                    #pragma unroll
                    for (int m = 1; m < 16; m <<= 1) sv += __shfl_xor(sv, m, 16);
                    if (l == 0) sbuf[(mt << 6) + (wv << 4) + (q << 2) + r] = sv;
                }
        }
        __syncthreads();                               // B8

        // ---- P8: out = Â·s (norms from regs) ----
        #pragma unroll
        for (int p = 0; p < 4; ++p) {
            const int r = grp + (p << 5);
            float acc8 = 0.f;
            #pragma unroll
            for (int e = 0; e < 3; ++e)
                acc8 = fmaf(nvr[p * 3 + e], sbuf[su[p * 3 + e] & 127u], acc8);
            acc8 += __shfl_xor(acc8, 1, 8);
            acc8 += __shfl_xor(acc8, 2, 8);
            acc8 += __shfl_xor(acc8, 4, 8);
            if (l8 == 0) out[(size_t)graph * NUMK + r] = acc8 + b3v;
        }

        // ---- rotate prefetched regs; protect degv/wshp/pbuf for next graph ----
        if (gi + 1 < GPB) {
            wcur = wnxt; pcur = pnxt;
            __syncthreads();                           // B9 (sbuf reads done)
        }
    }
}

extern "C" void kernel_launch(void* const* d_in, const int* in_sizes, int n_in,
                              void* d_out, int out_size, void* d_ws, size_t ws_size,
                              hipStream_t stream) {
    const float* Hx = (const float*)d_in[0];
    const int*   ei = (const int*)d_in[1];
    const float* W1 = (const float*)d_in[2];
    const float* b1 = (const float*)d_in[3];
    const float* W2 = (const float*)d_in[4];
    const float* b2 = (const float*)d_in[5];
    const float* W3 = (const float*)d_in[6];
    const float* b3 = (const float*)d_in[7];
    float* out = (float*)d_out;

    unsigned* pslot = (unsigned*)d_ws;                 // [NPS]
    unsigned* vmeta = pslot + NPS;                     // [1 + MAXV]

    build_csr_kernel<<<1, 1024, 0, stream>>>(ei, pslot, vmeta);
    gcn_main_kernel<<<GRID, 256, 0, stream>>>(Hx, W1, b1, W2, b2, W3, b3,
                                              pslot, vmeta, out);
}

// Round 11
// 102.223 us; speedup vs baseline: 1.4920x; 1.0945x over previous
//
#include <hip/hip_runtime.h>
#include <hip/hip_bf16.h>

#define NB    2048
#define NUMK  128
#define NE    1024
#define HID   32
#define ROWLEN (NUMK + NE + 2)
#define CAP   24                 // padded slots per row (unique srcs + self)
#define NPS   (NUMK * CAP)       // 3072
#define ASTRIDE 136              // bf16 elems per Â row (128 + 8 pad)
#define X1STRIDE 72              // bf16 elems per x1T-half row (64 + 8 pad)
#define W2STRIDE 40              // bf16 elems per a1/W2T row (32 + 8 pad)
#define WSELF 1024               // widx of self-loop weight (1.0)
#define WPAD  1025               // widx of pad weight (0.0)
#define WVBASE 1026              // first vslot (chained dup merges)
#define MAXV  16
#define WTOT  (WVBASE + MAXV)    // 1042

// slot encoding: src(7) | widx(11)<<7 | widx2(11)<<18 | prim(1)<<29
// pslot layout (coalesced for 512 thr, 4 lanes/row x 6 slots):
//   pslot_g[e*512 + row*4 + l4] = psl[row][l4*6 + e],  e in [0,6)
// vmeta: [0]=vcnt; [1+v] = a(11) | b(11)<<11 ; resolved on thread 0 from
//   GLOBAL weights during staging (chains reference earlier v -> in-order).
// w2tg (in ws, set up once): w2tg[n*40 + k] = bf16(W2[k][n])  (B-frag layout)

using s8  = __attribute__((ext_vector_type(8))) short;   // 8 bf16 = 16 B
using s4v = __attribute__((ext_vector_type(4))) short;   // 4 bf16 = 8 B
using f4  = __attribute__((ext_vector_type(4))) float;
using fl4 = __attribute__((ext_vector_type(4))) float;

static __device__ __forceinline__ unsigned short f2bf(float f) {
    unsigned u = __float_as_uint(f);
    unsigned r = (u + 0x7fffu + ((u >> 16) & 1u)) >> 16;   // RNE
    return (unsigned short)r;
}

// ---------------------------------------------------------------------------
// Setup (once): CSR by dst, per-row dedup into (widx, widx2 [, vslot chain]);
// also pre-pack W2^T in bf16 B-fragment layout into ws.
// ---------------------------------------------------------------------------
__global__ __launch_bounds__(1024) void build_csr_kernel(
    const int* __restrict__ ei,
    const float* __restrict__ W2,
    unsigned* __restrict__ pslot_g,    // [NPS]
    short* __restrict__ w2tg,          // [HID * W2STRIDE]
    unsigned* __restrict__ vmeta_g)    // [1 + MAXV]
{
    __shared__ unsigned cnt[NUMK], roff[NUMK + 1], cur[NUMK], incl[NUMK];
    __shared__ unsigned pk[NE];
    __shared__ unsigned psl[NUMK][CAP];
    __shared__ unsigned vc;
    const int t = threadIdx.x;

    if (t < NUMK) cnt[t] = 0u;
    if (t == 0) vc = 0u;
    {   // W2^T bf16 pack: w2tg[n*40+k] = bf16(W2[k*32+n])
        const int k = t >> 5, n = t & 31;
        w2tg[n * W2STRIDE + k] = (short)f2bf(W2[t]);
    }
    __syncthreads();
    const int dst = ei[NE + t] & (NUMK - 1);
    atomicAdd(&cnt[dst], 1u);
    __syncthreads();

    if (t < NUMK) {                              // exclusive scan (2 wave scans)
        unsigned v = cnt[t];
        #pragma unroll
        for (int d = 1; d < 64; d <<= 1) {
            unsigned u = __shfl_up(v, d, 64);
            if ((t & 63) >= d) v += u;
        }
        incl[t] = v;
    }
    __syncthreads();
    if (t < NUMK) {
        const unsigned base = (t >= 64) ? incl[63] : 0u;
        const unsigned off  = base + incl[t] - cnt[t];
        roff[t] = off; cur[t] = off;
    }
    if (t == 0) roff[NUMK] = (unsigned)NE;
    __syncthreads();

    {
        const int src = ei[t] & (NUMK - 1);
        const unsigned pos = atomicAdd(&cur[dst], 1u);
        pk[pos] = (unsigned)src | ((unsigned)t << 16);
    }
    __syncthreads();

    if (t < NUMK) {
        int np = 0;
        auto addOrMerge = [&](unsigned s, unsigned eid) {
            int j = -1;
            for (int i = 0; i < np; ++i)
                if ((psl[t][i] & 127u) == s) { j = i; break; }
            if (j >= 0) {
                const unsigned slot = psl[t][j];
                const unsigned w2x = (slot >> 18) & 0x7FFu;
                if (w2x == (unsigned)WPAD) {
                    psl[t][j] = (slot & ~(0x7FFu << 18)) | (eid << 18);
                } else {
                    const unsigned v = atomicAdd(&vc, 1u);
                    if (v < (unsigned)MAXV) {
                        vmeta_g[1 + v] = w2x | (eid << 11);
                        psl[t][j] = (slot & ~(0x7FFu << 18))
                                  | (((unsigned)WVBASE + v) << 18);
                    }
                }
            } else if (np < CAP) {
                psl[t][np++] = s | (eid << 7)
                             | ((unsigned)WPAD << 18) | (1u << 29);
            }
        };
        const unsigned k0 = roff[t], k1 = roff[t + 1];
        for (unsigned k = k0; k < k1; ++k)
            addOrMerge(pk[k] & 127u, pk[k] >> 16);
        addOrMerge((unsigned)t, (unsigned)WSELF);        // self-loop, w = 1
        for (int i = np; i < CAP; ++i)                   // pads: w = 0, prim = 0
            psl[t][i] = ((unsigned)WPAD << 7) | ((unsigned)WPAD << 18);
    }
    __syncthreads();

    for (int i = t; i < NPS; i += 1024) {
        const int e = i >> 9, rem = i & 511;
        const int r = rem >> 2, l4i = rem & 3;
        pslot_g[i] = psl[r][l4i * 6 + e];
    }
    if (t == 0) vmeta_g[0] = (vc <= (unsigned)MAXV) ? vc : (unsigned)MAXV;
}

// ---------------------------------------------------------------------------
// Main: one block (512 thr = 8 waves) per graph; 40,520 B LDS -> up to 4
// blocks/CU. Single full-A^ MFMA pass (8 waves x 16 exclusive rows); x1T in
// two 64-K halves unioned over dead wshp/pbuf; a1 written into each wave's
// OWN A^ rows (DS in-order, no barrier); W2 frags + biases from global.
// 7 barriers total.
// ---------------------------------------------------------------------------
__global__ __launch_bounds__(512, 6) void gcn_main_kernel(
    const float* __restrict__ Hx,
    const float* __restrict__ W1, const float* __restrict__ b1,
    const float* __restrict__ b2, const float* __restrict__ W3,
    const float* __restrict__ b3,
    const unsigned* __restrict__ pslot_g,
    const short*    __restrict__ w2tg,
    const unsigned* __restrict__ vmeta_g,
    float* __restrict__ out)
{
    __shared__ __align__(16) short Ab[NUMK * ASTRIDE];    // 34816 B
    __shared__ __align__(16) unsigned char ubuf[4680];    // wshp+pbuf | x1h
    __shared__ float degv[NUMK];                          //   512 B (dinv->sbuf)
    __shared__ float a0s[NUMK];                           //   512 B
    // total 40,520 B

    float* wshp = (float*)ubuf;                 // [WTOT]
    float* pbuf = (float*)(ubuf + WTOT * 4);    // [NUMK]
    short* x1h  = (short*)ubuf;                 // [HID * X1STRIDE] (after P4)

    const int tid = threadIdx.x;                // 0..511
    const int row = tid >> 2, l4 = tid & 3;     // 128 rows x 4 lanes
    const int wv = tid >> 6, lane = tid & 63;
    const int l = lane & 15, q = lane >> 4;
    const float* rowp = Hx + (size_t)blockIdx.x * ROWLEN;

    // ---- persistent loads (global; L2-hot small arrays) ----
    unsigned su[6];
    #pragma unroll
    for (int e = 0; e < 6; ++e) su[e] = pslot_g[(e << 9) + tid];
    const float b3v = b3[0];
    const float b2a = b2[l], b2b = b2[l + 16];
    const float w3a = W3[l], w3b = W3[l + 16];
    const int jj = tid >> 4;                    // x1T row 0..31
    const float w1j = W1[jj], b1j = b1[jj];
    const unsigned vcnt = vmeta_g[0];

    // ---- stage: zero A^, weights, signals; vslot chains via GLOBAL reads ----
    for (int t2 = tid; t2 < (NUMK * ASTRIDE) / 8; t2 += 512)
        *(s8*)&Ab[t2 * 8] = (s8)0;
    *(float2*)&wshp[tid * 2] = *(const float2*)&rowp[NUMK + tid * 2];
    if (tid == 511) { wshp[WSELF] = 1.0f; wshp[WPAD] = 0.0f; }
    if (tid < NUMK) pbuf[tid] = rowp[tid];
    if (tid == 0 && vcnt) {
        for (unsigned v = 0; v < vcnt; ++v) {
            const unsigned e = vmeta_g[1 + v];
            const unsigned a = e & 0x7FFu, b = (e >> 11) & 0x7FFu;
            const float wa = (a < 1024u) ? rowp[NUMK + a]
                           : (a == (unsigned)WSELF ? 1.0f : wshp[a]);  // own earlier write
            const float wb = (b < 1024u) ? rowp[NUMK + b]
                           : (b == (unsigned)WSELF ? 1.0f : wshp[b]);
            wshp[WVBASE + v] = wa + wb;
        }
    }
    __syncthreads();                                   // B1

    // ---- P2: merged slot weights + deg -> dinv (4-lane butterfly) ----
    float nvr[6];
    {
        float d = 0.f;
        #pragma unroll
        for (int e = 0; e < 6; ++e) {
            const unsigned u = su[e];
            nvr[e] = wshp[(u >> 7) & 0x7FFu] + wshp[(u >> 18) & 0x7FFu];
            d += nvr[e];
        }
        d += __shfl_xor(d, 1, 4);
        d += __shfl_xor(d, 2, 4);
        if (l4 == 0) degv[row] = rsqrtf(d);            // deg >= 1 (self w=1)
    }
    __syncthreads();                                   // B2

    // ---- P4: norms + A^ scatter (own row) + a0 = A^·p ----
    {
        const float dr = degv[row];
        float acc = 0.f;
        #pragma unroll
        for (int e = 0; e < 6; ++e) {
            const unsigned u = su[e];
            const int s = (int)(u & 127u);
            const float nv = (u >> 29) ? dr * degv[s] * nvr[e] : 0.f;
            if (u >> 29) Ab[row * ASTRIDE + s] = (short)f2bf(nv);
            nvr[e] = nv;
            acc = fmaf(nv, pbuf[s], acc);
        }
        acc += __shfl_xor(acc, 1, 4);
        acc += __shfl_xor(acc, 2, 4);
        if (l4 == 0) a0s[row] = acc;
    }
    __syncthreads();                                   // B3 (wshp/pbuf now dead)

    // ---- layer-2 propagate: a1 = A^ @ x1, x1 built in two 64-K halves ----
    f4 accm0 = {0.f,0.f,0.f,0.f}, accm1 = {0.f,0.f,0.f,0.f};
    const int arow = (wv << 4) + l;                    // wave-exclusive A^ row
    #pragma unroll
    for (int half = 0; half < 2; ++half) {
        {   // build x1T half: x1h[j][k] = relu(a0[64h+k]*w1[j]+b1[j])
            const int kk = (tid & 15) << 2;            // 0..60
            const fl4 av = *(const fl4*)&a0s[(half << 6) + kk];
            const unsigned p0 =
                  (unsigned)f2bf(fmaxf(fmaf(av[0], w1j, b1j), 0.f))
                | ((unsigned)f2bf(fmaxf(fmaf(av[1], w1j, b1j), 0.f)) << 16);
            const unsigned p1 =
                  (unsigned)f2bf(fmaxf(fmaf(av[2], w1j, b1j), 0.f))
                | ((unsigned)f2bf(fmaxf(fmaf(av[3], w1j, b1j), 0.f)) << 16);
            union { unsigned u[2]; s4v v; } P;
            P.u[0] = p0; P.u[1] = p1;
            *(s4v*)&x1h[jj * X1STRIDE + kk] = P.v;
        }
        __syncthreads();                               // B4 / B6
        #pragma unroll
        for (int ks2 = 0; ks2 < 2; ++ks2) {
            const int kloc = (ks2 << 5) + (q << 3);
            const s8 A  = *(const s8*)&Ab[arow * ASTRIDE + (half << 6) + kloc];
            const s8 B0 = *(const s8*)&x1h[l * X1STRIDE + kloc];
            const s8 B1 = *(const s8*)&x1h[(16 + l) * X1STRIDE + kloc];
            accm0 = __builtin_amdgcn_mfma_f32_16x16x32_bf16(A, B0, accm0, 0, 0, 0);
            accm1 = __builtin_amdgcn_mfma_f32_16x16x32_bf16(A, B1, accm1, 0, 0, 0);
        }
        if (half == 0) __syncthreads();                // B5 (x1h reads done)
    }

    // ---- a1 -> own A^ rows (same wave, DS in-order: no barrier) ----
    short* a1w = &Ab[(wv << 4) * ASTRIDE];             // 16 rows x W2STRIDE
    #pragma unroll
    for (int r = 0; r < 4; ++r) {
        const int tr = (q << 2) + r;
        a1w[tr * W2STRIDE + l]      = (short)f2bf(accm0[r]);
        a1w[tr * W2STRIDE + 16 + l] = (short)f2bf(accm1[r]);
    }

    // ---- P7: x2 = relu(a1@W2+b2); s = x2@W3 (same-wave; W2 frags global) ----
    {
        const s8 A0  = *(const s8*)&a1w[l * W2STRIDE + (q << 3)];
        const s8 Bw0 = *(const s8*)&w2tg[l * W2STRIDE + (q << 3)];
        const s8 Bw1 = *(const s8*)&w2tg[(16 + l) * W2STRIDE + (q << 3)];
        f4 ac20 = {0.f,0.f,0.f,0.f}, ac21 = {0.f,0.f,0.f,0.f};
        ac20 = __builtin_amdgcn_mfma_f32_16x16x32_bf16(A0, Bw0, ac20, 0, 0, 0);
        ac21 = __builtin_amdgcn_mfma_f32_16x16x32_bf16(A0, Bw1, ac21, 0, 0, 0);

        float* sbuf = degv;                            // dinv dead after P4
        #pragma unroll
        for (int r = 0; r < 4; ++r) {
            const float v0 = fmaxf(ac20[r] + b2a, 0.f);
            const float v1 = fmaxf(ac21[r] + b2b, 0.f);
            float sv = v0 * w3a + v1 * w3b;
            #pragma unroll
            for (int m = 1; m < 16; m <<= 1) sv += __shfl_xor(sv, m, 16);
            if (l == 0) sbuf[(wv << 4) + (q << 2) + r] = sv;
        }
    }
    __syncthreads();                                   // B7

    // ---- P8: out = A^·s (norms from regs) ----
    {
        float* sbuf = degv;
        float acc8 = 0.f;
        #pragma unroll
        for (int e = 0; e < 6; ++e)
            acc8 = fmaf(nvr[e], sbuf[su[e] & 127u], acc8);
        acc8 += __shfl_xor(acc8, 1, 4);
        acc8 += __shfl_xor(acc8, 2, 4);
        if (l4 == 0) out[(size_t)blockIdx.x * NUMK + row] = acc8 + b3v;
    }
}

extern "C" void kernel_launch(void* const* d_in, const int* in_sizes, int n_in,
                              void* d_out, int out_size, void* d_ws, size_t ws_size,
                              hipStream_t stream) {
    const float* Hx = (const float*)d_in[0];
    const int*   ei = (const int*)d_in[1];
    const float* W1 = (const float*)d_in[2];
    const float* b1 = (const float*)d_in[3];
    const float* W2 = (const float*)d_in[4];
    const float* b2 = (const float*)d_in[5];
    const float* W3 = (const float*)d_in[6];
    const float* b3 = (const float*)d_in[7];
    float* out = (float*)d_out;

    unsigned* pslot = (unsigned*)d_ws;                 // [NPS]      (12288 B)
    short*    w2tg  = (short*)(pslot + NPS);           // [32*40]    ( 2560 B, 16B-aligned)
    unsigned* vmeta = (unsigned*)(w2tg + HID * W2STRIDE); // [1+MAXV]

    build_csr_kernel<<<1, 1024, 0, stream>>>(ei, W2, pslot, w2tg, vmeta);
    gcn_main_kernel<<<NB, 512, 0, stream>>>(Hx, W1, b1, b2, W3, b3,
                                            pslot, w2tg, vmeta, out);
}

// Round 12
// 102.180 us; speedup vs baseline: 1.4926x; 1.0004x over previous
//
#include <hip/hip_runtime.h>
#include <hip/hip_bf16.h>

#define NB    2048
#define NUMK  128
#define NE    1024
#define HID   32
#define ROWLEN (NUMK + NE + 2)
#define CAP   24                 // padded slots per row (unique srcs + self)
#define NPS   (NUMK * CAP)       // 3072
#define ASTRIDE 136              // bf16 elems per Â row (128 + 8 pad)
#define X1STRIDE 72              // bf16 elems per x1T-half row (64 + 8 pad)
#define W2STRIDE 40              // bf16 elems per a1/W2T row (32 + 8 pad)
#define WSELF 1024               // widx of self-loop weight (1.0)
#define WPAD  1025               // widx of pad weight (0.0)
#define WVBASE 1026              // first vslot (chained dup merges)
#define MAXV  16
#define WTOT  (WVBASE + MAXV)    // 1042

// slot encoding: src(7) | widx(11)<<7 | widx2(11)<<18 | prim(1)<<29
// pslot layout (coalesced for 512 thr, 4 lanes/row x 6 slots):
//   pslot_g[e*512 + row*4 + l4] = psl[row][l4*6 + e],  e in [0,6)
// vmeta: [0]=vcnt; [1+v] = a(11) | b(11)<<11 ; resolved on thread 0 from
//   GLOBAL weights during staging (chains reference earlier v -> in-order).
// w2tg (in ws, set up once): w2tg[n*40 + k] = bf16(W2[k][n])  (B-frag layout)

using s8  = __attribute__((ext_vector_type(8))) short;   // 8 bf16 = 16 B
using s4v = __attribute__((ext_vector_type(4))) short;   // 4 bf16 = 8 B
using f4  = __attribute__((ext_vector_type(4))) float;
using fl4 = __attribute__((ext_vector_type(4))) float;

static __device__ __forceinline__ unsigned short f2bf(float f) {
    unsigned u = __float_as_uint(f);
    unsigned r = (u + 0x7fffu + ((u >> 16) & 1u)) >> 16;   // RNE
    return (unsigned short)r;
}

// ---------------------------------------------------------------------------
// Setup (once): CSR by dst, per-row dedup into (widx, widx2 [, vslot chain]);
// also pre-pack W2^T in bf16 B-fragment layout into ws.
// ---------------------------------------------------------------------------
__global__ __launch_bounds__(1024) void build_csr_kernel(
    const int* __restrict__ ei,
    const float* __restrict__ W2,
    unsigned* __restrict__ pslot_g,    // [NPS]
    short* __restrict__ w2tg,          // [HID * W2STRIDE]
    unsigned* __restrict__ vmeta_g)    // [1 + MAXV]
{
    __shared__ unsigned cnt[NUMK], roff[NUMK + 1], cur[NUMK], incl[NUMK];
    __shared__ unsigned pk[NE];
    __shared__ unsigned psl[NUMK][CAP];
    __shared__ unsigned vc;
    const int t = threadIdx.x;

    if (t < NUMK) cnt[t] = 0u;
    if (t == 0) vc = 0u;
    {   // W2^T bf16 pack: w2tg[n*40+k] = bf16(W2[k*32+n])
        const int k = t >> 5, n = t & 31;
        w2tg[n * W2STRIDE + k] = (short)f2bf(W2[t]);
    }
    __syncthreads();
    const int dst = ei[NE + t] & (NUMK - 1);
    atomicAdd(&cnt[dst], 1u);
    __syncthreads();

    if (t < NUMK) {                              // exclusive scan (2 wave scans)
        unsigned v = cnt[t];
        #pragma unroll
        for (int d = 1; d < 64; d <<= 1) {
            unsigned u = __shfl_up(v, d, 64);
            if ((t & 63) >= d) v += u;
        }
        incl[t] = v;
    }
    __syncthreads();
    if (t < NUMK) {
        const unsigned base = (t >= 64) ? incl[63] : 0u;
        const unsigned off  = base + incl[t] - cnt[t];
        roff[t] = off; cur[t] = off;
    }
    if (t == 0) roff[NUMK] = (unsigned)NE;
    __syncthreads();

    {
        const int src = ei[t] & (NUMK - 1);
        const unsigned pos = atomicAdd(&cur[dst], 1u);
        pk[pos] = (unsigned)src | ((unsigned)t << 16);
    }
    __syncthreads();

    if (t < NUMK) {
        int np = 0;
        auto addOrMerge = [&](unsigned s, unsigned eid) {
            int j = -1;
            for (int i = 0; i < np; ++i)
                if ((psl[t][i] & 127u) == s) { j = i; break; }
            if (j >= 0) {
                const unsigned slot = psl[t][j];
                const unsigned w2x = (slot >> 18) & 0x7FFu;
                if (w2x == (unsigned)WPAD) {
                    psl[t][j] = (slot & ~(0x7FFu << 18)) | (eid << 18);
                } else {
                    const unsigned v = atomicAdd(&vc, 1u);
                    if (v < (unsigned)MAXV) {
                        vmeta_g[1 + v] = w2x | (eid << 11);
                        psl[t][j] = (slot & ~(0x7FFu << 18))
                                  | (((unsigned)WVBASE + v) << 18);
                    }
                }
            } else if (np < CAP) {
                psl[t][np++] = s | (eid << 7)
                             | ((unsigned)WPAD << 18) | (1u << 29);
            }
        };
        const unsigned k0 = roff[t], k1 = roff[t + 1];
        for (unsigned k = k0; k < k1; ++k)
            addOrMerge(pk[k] & 127u, pk[k] >> 16);
        addOrMerge((unsigned)t, (unsigned)WSELF);        // self-loop, w = 1
        for (int i = np; i < CAP; ++i)                   // pads: w = 0, prim = 0
            psl[t][i] = ((unsigned)WPAD << 7) | ((unsigned)WPAD << 18);
    }
    __syncthreads();

    for (int i = t; i < NPS; i += 1024) {
        const int e = i >> 9, rem = i & 511;
        const int r = rem >> 2, l4i = rem & 3;
        pslot_g[i] = psl[r][l4i * 6 + e];
    }
    if (t == 0) vmeta_g[0] = (vc <= (unsigned)MAXV) ? vc : (unsigned)MAXV;
}

// ---------------------------------------------------------------------------
// Main: one block (512 thr = 8 waves) per graph; 40,448 B LDS.
// __launch_bounds__(512, 8): 64-reg budget -> 8 waves/SIMD -> 4 blocks/CU
// (R11 allowed up to ~85 regs, possibly capping at 3 blocks/CU). Live state
// trimmed to fit: su reloaded in P8; epilogue scalars loaded at use sites.
// Dataflow identical to validated R11. 7 barriers.
// ---------------------------------------------------------------------------
__global__ __launch_bounds__(512, 8) void gcn_main_kernel(
    const float* __restrict__ Hx,
    const float* __restrict__ W1, const float* __restrict__ b1,
    const float* __restrict__ b2, const float* __restrict__ W3,
    const float* __restrict__ b3,
    const unsigned* __restrict__ pslot_g,
    const short*    __restrict__ w2tg,
    const unsigned* __restrict__ vmeta_g,
    float* __restrict__ out)
{
    __shared__ __align__(16) short Ab[NUMK * ASTRIDE];    // 34816 B
    __shared__ __align__(16) unsigned char ubuf[4680];    // wshp+pbuf | x1h
    __shared__ float degv[NUMK];                          //   512 B (dinv->sbuf)
    __shared__ float a0s[NUMK];                           //   512 B

    float* wshp = (float*)ubuf;                 // [WTOT]
    float* pbuf = (float*)(ubuf + WTOT * 4);    // [NUMK]
    short* x1h  = (short*)ubuf;                 // [HID * X1STRIDE] (after P4)

    const int tid = threadIdx.x;                // 0..511
    const int row = tid >> 2, l4 = tid & 3;     // 128 rows x 4 lanes
    const int wv = tid >> 6, lane = tid & 63;
    const int l = lane & 15, q = lane >> 4;
    const float* rowp = Hx + (size_t)blockIdx.x * ROWLEN;

    // ---- slot loads (live only through P4; reloaded for P8) ----
    unsigned su[6];
    #pragma unroll
    for (int e = 0; e < 6; ++e) su[e] = pslot_g[(e << 9) + tid];
    const unsigned vcnt = vmeta_g[0];

    // ---- stage: zero A^, weights, signals; vslot chains via GLOBAL reads ----
    for (int t2 = tid; t2 < (NUMK * ASTRIDE) / 8; t2 += 512)
        *(s8*)&Ab[t2 * 8] = (s8)0;
    *(float2*)&wshp[tid * 2] = *(const float2*)&rowp[NUMK + tid * 2];
    if (tid == 511) { wshp[WSELF] = 1.0f; wshp[WPAD] = 0.0f; }
    if (tid < NUMK) pbuf[tid] = rowp[tid];
    if (tid == 0 && vcnt) {
        for (unsigned v = 0; v < vcnt; ++v) {
            const unsigned e = vmeta_g[1 + v];
            const unsigned a = e & 0x7FFu, b = (e >> 11) & 0x7FFu;
            const float wa = (a < 1024u) ? rowp[NUMK + a]
                           : (a == (unsigned)WSELF ? 1.0f : wshp[a]);
            const float wb = (b < 1024u) ? rowp[NUMK + b]
                           : (b == (unsigned)WSELF ? 1.0f : wshp[b]);
            wshp[WVBASE + v] = wa + wb;
        }
    }
    __syncthreads();                                   // B1

    // ---- P2: merged slot weights + deg -> dinv (4-lane butterfly) ----
    float nvr[6];
    {
        float d = 0.f;
        #pragma unroll
        for (int e = 0; e < 6; ++e) {
            const unsigned u = su[e];
            nvr[e] = wshp[(u >> 7) & 0x7FFu] + wshp[(u >> 18) & 0x7FFu];
            d += nvr[e];
        }
        d += __shfl_xor(d, 1, 4);
        d += __shfl_xor(d, 2, 4);
        if (l4 == 0) degv[row] = rsqrtf(d);            // deg >= 1 (self w=1)
    }
    __syncthreads();                                   // B2

    // ---- P4: norms + A^ scatter (own row) + a0 = A^·p ----
    {
        const float dr = degv[row];
        float acc = 0.f;
        #pragma unroll
        for (int e = 0; e < 6; ++e) {
            const unsigned u = su[e];
            const int s = (int)(u & 127u);
            const float nv = (u >> 29) ? dr * degv[s] * nvr[e] : 0.f;
            if (u >> 29) Ab[row * ASTRIDE + s] = (short)f2bf(nv);
            nvr[e] = nv;
            acc = fmaf(nv, pbuf[s], acc);
        }
        acc += __shfl_xor(acc, 1, 4);
        acc += __shfl_xor(acc, 2, 4);
        if (l4 == 0) a0s[row] = acc;
    }
    __syncthreads();                                   // B3 (wshp/pbuf now dead)

    // ---- layer-2 propagate: a1 = A^ @ x1, x1 built in two 64-K halves ----
    f4 accm0 = {0.f,0.f,0.f,0.f}, accm1 = {0.f,0.f,0.f,0.f};
    const int arow = (wv << 4) + l;                    // wave-exclusive A^ row
    #pragma unroll
    for (int half = 0; half < 2; ++half) {
        {   // build x1h half: x1h[j][k] = relu(a0[64h+k]*w1[j]+b1[j])
            const int jj = tid >> 4;                   // x1T row 0..31
            const float w1j = W1[jj], b1j = b1[jj];    // L2-hot reload
            const int kk = (tid & 15) << 2;            // 0..60
            const fl4 av = *(const fl4*)&a0s[(half << 6) + kk];
            const unsigned p0 =
                  (unsigned)f2bf(fmaxf(fmaf(av[0], w1j, b1j), 0.f))
                | ((unsigned)f2bf(fmaxf(fmaf(av[1], w1j, b1j), 0.f)) << 16);
            const unsigned p1 =
                  (unsigned)f2bf(fmaxf(fmaf(av[2], w1j, b1j), 0.f))
                | ((unsigned)f2bf(fmaxf(fmaf(av[3], w1j, b1j), 0.f)) << 16);
            union { unsigned u[2]; s4v v; } P;
            P.u[0] = p0; P.u[1] = p1;
            *(s4v*)&x1h[jj * X1STRIDE + kk] = P.v;
        }
        __syncthreads();                               // B4 / B6
        #pragma unroll
        for (int ks2 = 0; ks2 < 2; ++ks2) {
            const int kloc = (ks2 << 5) + (q << 3);
            const s8 A  = *(const s8*)&Ab[arow * ASTRIDE + (half << 6) + kloc];
            const s8 B0 = *(const s8*)&x1h[l * X1STRIDE + kloc];
            const s8 B1 = *(const s8*)&x1h[(16 + l) * X1STRIDE + kloc];
            accm0 = __builtin_amdgcn_mfma_f32_16x16x32_bf16(A, B0, accm0, 0, 0, 0);
            accm1 = __builtin_amdgcn_mfma_f32_16x16x32_bf16(A, B1, accm1, 0, 0, 0);
        }
        if (half == 0) __syncthreads();                // B5 (x1h reads done)
    }

    // ---- a1 -> own A^ rows (same wave, DS in-order: no barrier) ----
    short* a1w = &Ab[(wv << 4) * ASTRIDE];             // 16 rows x W2STRIDE
    #pragma unroll
    for (int r = 0; r < 4; ++r) {
        const int tr = (q << 2) + r;
        a1w[tr * W2STRIDE + l]      = (short)f2bf(accm0[r]);
        a1w[tr * W2STRIDE + 16 + l] = (short)f2bf(accm1[r]);
    }

    // ---- P7: x2 = relu(a1@W2+b2); s = x2@W3 (same-wave; W2 frags global) ----
    {
        const s8 A0  = *(const s8*)&a1w[l * W2STRIDE + (q << 3)];
        const s8 Bw0 = *(const s8*)&w2tg[l * W2STRIDE + (q << 3)];
        const s8 Bw1 = *(const s8*)&w2tg[(16 + l) * W2STRIDE + (q << 3)];
        f4 ac20 = {0.f,0.f,0.f,0.f}, ac21 = {0.f,0.f,0.f,0.f};
        ac20 = __builtin_amdgcn_mfma_f32_16x16x32_bf16(A0, Bw0, ac20, 0, 0, 0);
        ac21 = __builtin_amdgcn_mfma_f32_16x16x32_bf16(A0, Bw1, ac21, 0, 0, 0);

        const float b2a = b2[l], b2b = b2[l + 16];     // L2-hot, loaded at use
        const float w3a = W3[l], w3b = W3[l + 16];
        float* sbuf = degv;                            // dinv dead after P4
        #pragma unroll
        for (int r = 0; r < 4; ++r) {
            const float v0 = fmaxf(ac20[r] + b2a, 0.f);
            const float v1 = fmaxf(ac21[r] + b2b, 0.f);
            float sv = v0 * w3a + v1 * w3b;
            #pragma unroll
            for (int m = 1; m < 16; m <<= 1) sv += __shfl_xor(sv, m, 16);
            if (l == 0) sbuf[(wv << 4) + (q << 2) + r] = sv;
        }
    }
    __syncthreads();                                   // B7

    // ---- P8: out = A^·s (norms from regs; slots reloaded, L2-hot) ----
    {
        float* sbuf = degv;
        float acc8 = 0.f;
        #pragma unroll
        for (int e = 0; e < 6; ++e) {
            const unsigned u2 = pslot_g[(e << 9) + tid];
            acc8 = fmaf(nvr[e], sbuf[u2 & 127u], acc8);
        }
        acc8 += __shfl_xor(acc8, 1, 4);
        acc8 += __shfl_xor(acc8, 2, 4);
        if (l4 == 0) out[(size_t)blockIdx.x * NUMK + row] = acc8 + b3[0];
    }
}

extern "C" void kernel_launch(void* const* d_in, const int* in_sizes, int n_in,
                              void* d_out, int out_size, void* d_ws, size_t ws_size,
                              hipStream_t stream) {
    const float* Hx = (const float*)d_in[0];
    const int*   ei = (const int*)d_in[1];
    const float* W1 = (const float*)d_in[2];
    const float* b1 = (const float*)d_in[3];
    const float* W2 = (const float*)d_in[4];
    const float* b2 = (const float*)d_in[5];
    const float* W3 = (const float*)d_in[6];
    const float* b3 = (const float*)d_in[7];
    float* out = (float*)d_out;

    unsigned* pslot = (unsigned*)d_ws;                 // [NPS]      (12288 B)
    short*    w2tg  = (short*)(pslot + NPS);           // [32*40]    ( 2560 B, 16B-aligned)
    unsigned* vmeta = (unsigned*)(w2tg + HID * W2STRIDE); // [1+MAXV]

    build_csr_kernel<<<1, 1024, 0, stream>>>(ei, W2, pslot, w2tg, vmeta);
    gcn_main_kernel<<<NB, 512, 0, stream>>>(Hx, W1, b1, b2, W3, b3,
                                            pslot, w2tg, vmeta, out);
}